// Round 14
// baseline (2280.862 us; speedup 1.0000x reference)
//
#include <hip/hip_runtime.h>
#include <hip/hip_bf16.h>
#include <stdint.h>

// Problem constants (from reference)
#define B_      8
#define N_      16384
#define NPOINT  512
#define KNN_    16
#define C_      16

// Exact IEEE f32 ops — bit-match the numpy (ref=np) lowering:
//   p2/s2 : np.sum(v*v,-1)  -> pairwise small-n ASCENDING:  (x2+y2)+z2, no FMA
//   FPS d : np.sum(dd*dd,-1)-> ASCENDING:  (dx2+dy2)+dz2, no FMA
//   dot   : np.einsum unopt -> sum_of_products_contig_two remainder switch,
//           DESCENDING fallthrough:  ((sz*pz) + sy*py) + sx*px, no FMA
//   dist  : (s2 + p2) - 2*dot   elementwise, no FMA
__device__ __forceinline__ float fmulrn(float a, float b){ return __fmul_rn(a,b); }
__device__ __forceinline__ float faddrn(float a, float b){ return __fadd_rn(a,b); }
__device__ __forceinline__ float fsubrn(float a, float b){ return __fsub_rn(a,b); }

// ---------------------------------------------------------------------------
// DPP reductions (VALU pipe, zero LDS ops).
// ---------------------------------------------------------------------------
__device__ __forceinline__ uint32_t umax_(uint32_t a, uint32_t b){ return a > b ? a : b; }

// 4-step row_shr reduce: lane 15 of each 16-lane row = max of that row.
__device__ __forceinline__ uint32_t row16_max(uint32_t x){
    uint32_t t;
    t = (uint32_t)__builtin_amdgcn_update_dpp((int)x, (int)x, 0x111, 0xf, 0xf, false); x = umax_(x, t);
    t = (uint32_t)__builtin_amdgcn_update_dpp((int)x, (int)x, 0x112, 0xf, 0xf, false); x = umax_(x, t);
    t = (uint32_t)__builtin_amdgcn_update_dpp((int)x, (int)x, 0x114, 0xf, 0xf, false); x = umax_(x, t);
    t = (uint32_t)__builtin_amdgcn_update_dpp((int)x, (int)x, 0x118, 0xf, 0xf, false); x = umax_(x, t);
    return x;
}

// Full 64-lane max as a UNIFORM value: row reduce + 4 readlane + scalar max.
__device__ __forceinline__ uint32_t wave_max_uniform(uint32_t x){
    x = row16_max(x);
    uint32_t a = (uint32_t)__builtin_amdgcn_readlane((int)x, 15);
    uint32_t b = (uint32_t)__builtin_amdgcn_readlane((int)x, 31);
    uint32_t c = (uint32_t)__builtin_amdgcn_readlane((int)x, 47);
    uint32_t d = (uint32_t)__builtin_amdgcn_readlane((int)x, 63);
    return umax_(umax_(a, b), umax_(c, d));
}

// ---------------------------------------------------------------------------
// Kernel 1: pack {x, y, z, p2} per point.  p2 = (x*x + y*y) + z*z  (ascending).
// ---------------------------------------------------------------------------
__global__ void prep_kernel(const float* __restrict__ x, float4* __restrict__ pts){
    int i = blockIdx.x * blockDim.x + threadIdx.x;   // 0 .. B_*N_-1
    if (i >= B_ * N_) return;
    const float4* x4 = (const float4*)x;             // x row = 16 floats = 4 float4
    float4 q = x4[(size_t)i * 4];                    // channels 0..3: x,y,z,c3
    float p2 = faddrn(faddrn(fmulrn(q.x,q.x), fmulrn(q.y,q.y)), fmulrn(q.z,q.z));
    pts[i] = make_float4(q.x, q.y, q.z, p2);
}

// ---------------------------------------------------------------------------
// Kernel 1b: zero the mailbox (every launch — graph replays reuse ws; stale
// nonzero keys would satisfy the spin early).
// ---------------------------------------------------------------------------
#define FPS_NB   4
#define NWB      64                      // waves per batch = FPS_NB * 16
#define MBOX_N   (B_ * NPOINT * NWB)     // 262144 u64 = 2 MiB
__global__ void zero_part_kernel(unsigned long long* __restrict__ part){
    int i = blockIdx.x * blockDim.x + threadIdx.x;
    if (i < MBOX_N) part[i] = 0ULL;
}

// ---------------------------------------------------------------------------
// Kernel 2: multi-block FPS with PER-WAVE mailbox exchange (no __syncthreads
// in the loop). R13 post-mortem: the in-block reduce + 16-wave barrier sat in
// series with the L3 mailbox RT (3700 cyc/iter). Now each of the batch's 64
// waves publishes its own u64 key {hi = f32 bits of wave-max min_d, lo =
// ~global_idx}; every wave polls the 64-entry row (one entry per lane, one
// coalesced load) and combines with two DPP uniform reduces. max over keys ==
// (max val, min idx) == numpy first-occurrence argmax, bit-exact. Keys are
// never 0 -> nonzero IS the ready flag; mailbox re-zeroed per launch.
// Bounded spin bails out (fail fast, never hang). b=idx&7 keeps a batch's
// blocks on one XCD (heuristic, correctness-neutral).
// ---------------------------------------------------------------------------
#define FPS_T    1024
#define SLICE    (N_ / FPS_NB)       // 4096 points per block
#define FOR_S4(F) F(0) F(1) F(2) F(3)

__global__ void __launch_bounds__(FPS_T)
fps_kernel_mb(const float4* __restrict__ pts, float4* __restrict__ s_out,
              unsigned long long* __restrict__ part){
    __shared__ float2 xy[SLICE];                // 32 KiB slice of (x,y)

    const int b    = blockIdx.x & 7;            // batch (same XCD per batch)
    const int blk  = blockIdx.x >> 3;           // sub-block 0..FPS_NB-1
    const int tid  = threadIdx.x;
    const int lane = tid & 63;
    const int wid  = (blk << 4) | (tid >> 6);   // wave id in batch, 0..63
    const int base = blk * SLICE;               // global offset of this slice
    const float4* P = pts + (size_t)b * N_;
    unsigned long long* mbox = part + (size_t)b * NPOINT * NWB;

#define DECL_S(s) float z##s, md##s;
    FOR_S4(DECL_S)
#undef DECL_S

#define INIT_S(s) { float4 q = P[base + (s) * FPS_T + tid]; \
        xy[(s) * FPS_T + tid] = make_float2(q.x, q.y); \
        z##s = q.z; md##s = 1e10f; }
    FOR_S4(INIT_S)
#undef INIT_S

    float lx, ly, lz;
    {
        float4 q0 = P[0];                       // seed = index 0
        lx = q0.x; ly = q0.y; lz = q0.z;
        if (blk == 0 && tid == 0) s_out[(size_t)b * NPOINT + 0] = q0;
    }
    __syncthreads();                            // staging visible (only barrier)

    for (int it = 1; it < NPOINT; ++it){
        float    bv = -1.0f;                    // all min_d >= 0
        uint32_t bi = 0;                        // GLOBAL point index
        // slots ascend in global index -> strict > keeps first occurrence
#define DO_S(s) { \
        float2 c = xy[(s) * FPS_T + tid]; \
        float dx = fsubrn(c.x, lx); \
        float dy = fsubrn(c.y, ly); \
        float dz = fsubrn(z##s, lz); \
        float d  = faddrn(faddrn(fmulrn(dx,dx), fmulrn(dy,dy)), fmulrn(dz,dz)); \
        md##s = fminf(md##s, d); \
        if (md##s > bv){ bv = md##s; bi = (uint32_t)(base + (s) * FPS_T + tid); } }
        FOR_S4(DO_S)
#undef DO_S

        // ---- per-wave reduce (DPP, uniform) + publish ----
        uint32_t vb    = __float_as_uint(bv);
        uint32_t gmaxw = wave_max_uniform(vb);
        uint32_t gidxw = wave_max_uniform((vb == gmaxw) ? ~bi : 0u);
        unsigned long long kw =
            ((unsigned long long)gmaxw << 32) | gidxw;       // never 0
        unsigned long long* slot = mbox + (size_t)it * NWB;
        if (lane == 0)
            __hip_atomic_store(&slot[wid], kw, __ATOMIC_RELAXED,
                               __HIP_MEMORY_SCOPE_AGENT);
        // ---- poll: one entry per lane, coalesced ----
        unsigned long long v = 0;
        int guard = 0;
        for (;;){
            if (v == 0)
                v = __hip_atomic_load(&slot[lane], __ATOMIC_RELAXED,
                                      __HIP_MEMORY_SCOPE_AGENT);
            if (__all(v != 0ULL)) break;
            if (++guard > (1 << 20)) return;    // bail: fail fast, never hang
        }
        // ---- combine 64 wave-keys: (max val, then min idx) uniform ----
        uint32_t hi = (uint32_t)(v >> 32), lo = (uint32_t)v;
        uint32_t gv = wave_max_uniform(hi);
        uint32_t gn = wave_max_uniform((hi == gv) ? lo : 0u);
        uint32_t gi = ~gn;
        uint32_t giu = (uint32_t)__builtin_amdgcn_readfirstlane((int)gi);
        float4 q = P[giu];                      // uniform -> scalar load path
        lx = q.x; ly = q.y; lz = q.z;
        if (blk == 0 && tid == 0) s_out[(size_t)b * NPOINT + it] = q;
    }
}

// ---------------------------------------------------------------------------
// Kernel 3: exact 16-NN per sample row (one wave per row, 4 rows per block).
// R14 change: DEPENDENCE-FREE insertion step. Old cascade carried c through
// 16 dependent u64 cmp+cndmask links (~190 cyc latency each insert, gate
// fires ~every group). New: insertion-sort identity
//   v_t' = lt_t ? (lt_{t-1} ? v_{t-1} : c) : v_t,  lt_t = (c < v_t)
// 16 independent compares + independent slot updates (descending order reads
// only OLD values). Bit-identical results, 2-deep latency.
// ---------------------------------------------------------------------------
__global__ void __launch_bounds__(256)
__attribute__((amdgpu_waves_per_eu(4, 4)))
knn_kernel(const float* __restrict__ x,
           const float4* __restrict__ pts,
           const float4* __restrict__ s_arr,
           float* __restrict__ out){
    const int wv   = threadIdx.x >> 6;
    const int lane = threadIdx.x & 63;
    const int blk  = blockIdx.x;            // 0 .. B_*NPOINT/4 - 1
    const int b    = blk >> 7;              // 128 blocks per batch
    const int p    = ((blk & 127) << 2) | wv;

    const float4 s = s_arr[(size_t)b * NPOINT + p];
    const float sx = s.x, sy = s.y, sz = s.z, s2 = s.w;
    const float4* P = pts + (size_t)b * N_;

#define FOR_V(F) F(0) F(1) F(2) F(3) F(4) F(5) F(6) F(7) \
                 F(8) F(9) F(10) F(11) F(12) F(13) F(14) F(15)
#define DECLV(t) unsigned long long v##t = ~0ULL;
    FOR_V(DECLV)
#undef DECLV

#define PROC(q, n) { \
        float dot = faddrn(faddrn(fmulrn(sz, (q).z), fmulrn(sy, (q).y)), fmulrn(sx, (q).x)); \
        float d = fsubrn(faddrn(s2, (q).w), fmulrn(2.0f, dot)); \
        uint32_t bits = __float_as_uint(d); \
        uint32_t key  = bits ^ (((uint32_t)((int32_t)bits >> 31)) | 0x80000000u); \
        unsigned long long c = ((unsigned long long)key << 32) | (uint32_t)(n); \
        if (c < v15){ \
            bool lt0=c<v0,  lt1=c<v1,  lt2=c<v2,  lt3=c<v3; \
            bool lt4=c<v4,  lt5=c<v5,  lt6=c<v6,  lt7=c<v7; \
            bool lt8=c<v8,  lt9=c<v9,  lt10=c<v10, lt11=c<v11; \
            bool lt12=c<v12, lt13=c<v13, lt14=c<v14; \
            v15 = lt14 ? v14 : c; \
            v14 = lt14 ? (lt13 ? v13 : c) : v14; \
            v13 = lt13 ? (lt12 ? v12 : c) : v13; \
            v12 = lt12 ? (lt11 ? v11 : c) : v12; \
            v11 = lt11 ? (lt10 ? v10 : c) : v11; \
            v10 = lt10 ? (lt9  ? v9  : c) : v10; \
            v9  = lt9  ? (lt8  ? v8  : c) : v9;  \
            v8  = lt8  ? (lt7  ? v7  : c) : v8;  \
            v7  = lt7  ? (lt6  ? v6  : c) : v7;  \
            v6  = lt6  ? (lt5  ? v5  : c) : v6;  \
            v5  = lt5  ? (lt4  ? v4  : c) : v5;  \
            v4  = lt4  ? (lt3  ? v3  : c) : v4;  \
            v3  = lt3  ? (lt2  ? v2  : c) : v3;  \
            v2  = lt2  ? (lt1  ? v1  : c) : v2;  \
            v1  = lt1  ? (lt0  ? v0  : c) : v1;  \
            v0  = lt0  ? c : v0; \
        } }

    #pragma unroll 1
    for (int j = 0; j < N_/64; j += 4){
        const int n0 = (j << 6) | lane;
        float4 q0 = P[n0];
        float4 q1 = P[n0 + 64];
        float4 q2 = P[n0 + 128];
        float4 q3 = P[n0 + 192];
        PROC(q0, n0)
        PROC(q1, n0 + 64)
        PROC(q2, n0 + 128)
        PROC(q3, n0 + 192)
    }
#undef PROC

    // merge: 16 rounds of wave-min over per-lane heads; winner lane consumes.
    uint32_t myidx = 0;
    const int myr = lane >> 2;
    #pragma unroll 1
    for (int r = 0; r < KNN_; ++r){
        unsigned long long h = v0;
        unsigned long long g = h;
        #pragma unroll
        for (int off = 1; off < 64; off <<= 1){
            unsigned long long o = __shfl_xor(g, off, 64);
            if (o < g) g = o;
        }
        if (h == g){                          // unique winner (idx is unique)
            v0=v1; v1=v2; v2=v3; v3=v4; v4=v5; v5=v6; v6=v7; v7=v8;
            v8=v9; v9=v10; v10=v11; v11=v12; v12=v13; v13=v14; v14=v15;
            v15=~0ULL;
        }
        if (myr == r) myidx = (uint32_t)g;    // keep idx of my output row
    }

    // gather + write: lane l handles neighbor r=l>>2, channels 4*(l&3)..+3
    const int c4 = lane & 3;
    const float4* X4 = (const float4*)x;
    float4 valq = X4[((size_t)b * N_ + myidx) * 4 + c4];
    float4* O4 = (float4*)out;
    O4[(((size_t)b * NPOINT + p) * KNN_ + myr) * 4 + c4] = valq;
}

// ---------------------------------------------------------------------------
extern "C" void kernel_launch(void* const* d_in, const int* in_sizes, int n_in,
                              void* d_out, int out_size, void* d_ws, size_t ws_size,
                              hipStream_t stream) {
    const float* x = (const float*)d_in[0];
    float* out = (float*)d_out;

    // workspace: [pts: 2MB][s_arr: 64KB][mailbox: 2MB]
    const size_t pts_bytes  = (size_t)B_ * N_ * sizeof(float4);
    const size_t s_bytes    = (size_t)B_ * NPOINT * sizeof(float4);
    const size_t part_bytes = (size_t)MBOX_N * sizeof(unsigned long long);
    if (ws_size < pts_bytes + s_bytes + part_bytes) return;  // visible failure
    float4* pts   = (float4*)d_ws;
    float4* s_arr = (float4*)((char*)d_ws + pts_bytes);
    unsigned long long* part =
        (unsigned long long*)((char*)d_ws + pts_bytes + s_bytes);

    prep_kernel<<<(B_*N_ + 255)/256, 256, 0, stream>>>(x, pts);
    zero_part_kernel<<<(MBOX_N + 255)/256, 256, 0, stream>>>(part);
    fps_kernel_mb<<<B_*FPS_NB, FPS_T, 0, stream>>>(pts, s_arr, part);
    knn_kernel<<<(B_*NPOINT)/4, 256, 0, stream>>>(x, pts, s_arr, out);
}

// Round 15
// 1169.826 us; speedup vs baseline: 1.9497x; 1.9497x over previous
//
#include <hip/hip_runtime.h>
#include <hip/hip_bf16.h>
#include <stdint.h>

// Problem constants (from reference)
#define B_      8
#define N_      16384
#define NPOINT  512
#define KNN_    16
#define C_      16

// Exact IEEE f32 ops — bit-match the numpy (ref=np) lowering:
//   p2/s2 : np.sum(v*v,-1)  -> pairwise small-n ASCENDING:  (x2+y2)+z2, no FMA
//   FPS d : np.sum(dd*dd,-1)-> ASCENDING:  (dx2+dy2)+dz2, no FMA
//   dot   : np.einsum unopt -> sum_of_products_contig_two remainder switch,
//           DESCENDING fallthrough:  ((sz*pz) + sy*py) + sx*px, no FMA
//   dist  : (s2 + p2) - 2*dot   elementwise, no FMA
__device__ __forceinline__ float fmulrn(float a, float b){ return __fmul_rn(a,b); }
__device__ __forceinline__ float faddrn(float a, float b){ return __fadd_rn(a,b); }
__device__ __forceinline__ float fsubrn(float a, float b){ return __fsub_rn(a,b); }

// ---------------------------------------------------------------------------
// DPP reductions (VALU pipe, zero LDS ops).
// ---------------------------------------------------------------------------
__device__ __forceinline__ uint32_t umax_(uint32_t a, uint32_t b){ return a > b ? a : b; }

__device__ __forceinline__ uint32_t row16_max(uint32_t x){
    uint32_t t;
    t = (uint32_t)__builtin_amdgcn_update_dpp((int)x, (int)x, 0x111, 0xf, 0xf, false); x = umax_(x, t);
    t = (uint32_t)__builtin_amdgcn_update_dpp((int)x, (int)x, 0x112, 0xf, 0xf, false); x = umax_(x, t);
    t = (uint32_t)__builtin_amdgcn_update_dpp((int)x, (int)x, 0x114, 0xf, 0xf, false); x = umax_(x, t);
    t = (uint32_t)__builtin_amdgcn_update_dpp((int)x, (int)x, 0x118, 0xf, 0xf, false); x = umax_(x, t);
    return x;
}

__device__ __forceinline__ uint32_t wave_max_uniform(uint32_t x){
    x = row16_max(x);
    uint32_t a = (uint32_t)__builtin_amdgcn_readlane((int)x, 15);
    uint32_t b = (uint32_t)__builtin_amdgcn_readlane((int)x, 31);
    uint32_t c = (uint32_t)__builtin_amdgcn_readlane((int)x, 47);
    uint32_t d = (uint32_t)__builtin_amdgcn_readlane((int)x, 63);
    return umax_(umax_(a, b), umax_(c, d));
}

// u64 max across each quad (lanes 4k..4k+3): 2 quad_perm DPP steps.
__device__ __forceinline__ unsigned long long quad_max_u64(unsigned long long k){
    uint32_t lo = (uint32_t)k, hi = (uint32_t)(k >> 32);
    {   // quad_perm [1,0,3,2] = 0xB1
        uint32_t olo = (uint32_t)__builtin_amdgcn_update_dpp((int)lo, (int)lo, 0xB1, 0xf, 0xf, false);
        uint32_t ohi = (uint32_t)__builtin_amdgcn_update_dpp((int)hi, (int)hi, 0xB1, 0xf, 0xf, false);
        bool take = (ohi > hi) || (ohi == hi && olo > lo);
        hi = take ? ohi : hi; lo = take ? olo : lo;
    }
    {   // quad_perm [2,3,0,1] = 0x4E
        uint32_t olo = (uint32_t)__builtin_amdgcn_update_dpp((int)lo, (int)lo, 0x4E, 0xf, 0xf, false);
        uint32_t ohi = (uint32_t)__builtin_amdgcn_update_dpp((int)hi, (int)hi, 0x4E, 0xf, 0xf, false);
        bool take = (ohi > hi) || (ohi == hi && olo > lo);
        hi = take ? ohi : hi; lo = take ? olo : lo;
    }
    return ((unsigned long long)hi << 32) | lo;
}

// ---------------------------------------------------------------------------
// Kernel 1: pack {x, y, z, p2} per point.  p2 = (x*x + y*y) + z*z  (ascending).
// ---------------------------------------------------------------------------
__global__ void prep_kernel(const float* __restrict__ x, float4* __restrict__ pts){
    int i = blockIdx.x * blockDim.x + threadIdx.x;   // 0 .. B_*N_-1
    if (i >= B_ * N_) return;
    const float4* x4 = (const float4*)x;             // x row = 16 floats = 4 float4
    float4 q = x4[(size_t)i * 4];                    // channels 0..3: x,y,z,c3
    float p2 = faddrn(faddrn(fmulrn(q.x,q.x), fmulrn(q.y,q.y)), fmulrn(q.z,q.z));
    pts[i] = make_float4(q.x, q.y, q.z, p2);
}

// ---------------------------------------------------------------------------
// Kernel 1b: zero the mailbox (every launch — graph replays reuse ws).
// ---------------------------------------------------------------------------
#define FPS_NB   4
#define MBOX_N   (B_ * NPOINT * FPS_NB)    // 16384 u64 = 128 KiB
__global__ void zero_part_kernel(unsigned long long* __restrict__ part){
    int i = blockIdx.x * blockDim.x + threadIdx.x;
    if (i < MBOX_N) part[i] = 0ULL;
}

// ---------------------------------------------------------------------------
// Kernel 2: multi-block FPS, R13's proven 4-entry block mailbox protocol.
// R14 falsified per-wave mailboxes (poll traffic 10x, 2.6x slower). R15
// geometry: 256-thread blocks (4 waves) x 16 slots — same per-SIMD VALU
// issue, but 4-wave barrier (not 16), quad-DPP block combine (not row16),
// 4 polling waves per block (traffic /4), 16-slot ILP per wave.
// Key = {hi = f32 bits of block-max min_d, lo = ~global_idx}; max == (max
// val, min idx) == numpy first-occurrence argmax, bit-exact. Keys never 0 ->
// nonzero IS the ready flag; mailbox re-zeroed per launch; bounded spin
// bails out (fail fast). b=idx&7 keeps a batch's blocks on one XCD.
// ---------------------------------------------------------------------------
#define FPS_T    256
#define SLICE    (N_ / FPS_NB)       // 4096 points per block
#define FOR_SLOTS(F) F(0) F(1) F(2) F(3) F(4) F(5) F(6) F(7) \
                     F(8) F(9) F(10) F(11) F(12) F(13) F(14) F(15)

__global__ void __launch_bounds__(FPS_T)
fps_kernel_mb(const float4* __restrict__ pts, float4* __restrict__ s_out,
              unsigned long long* __restrict__ part){
    __shared__ float2 xy[SLICE];                // 32 KiB slice of (x,y)
    __shared__ unsigned long long red[2][4];    // per-wave keys, dbuf parity

    const int b    = blockIdx.x & 7;            // batch (same XCD per batch)
    const int blk  = blockIdx.x >> 3;           // sub-block 0..FPS_NB-1
    const int tid  = threadIdx.x;
    const int lane = tid & 63;
    const int wv   = tid >> 6;                  // wave 0..3
    const int base = blk * SLICE;               // global offset of this slice
    const float4* P = pts + (size_t)b * N_;
    unsigned long long* mbox = part + (size_t)b * NPOINT * FPS_NB;

#define DECL_S(s) float z##s, md##s;
    FOR_SLOTS(DECL_S)
#undef DECL_S

#define INIT_S(s) { float4 q = P[base + (s) * FPS_T + tid]; \
        xy[(s) * FPS_T + tid] = make_float2(q.x, q.y); \
        z##s = q.z; md##s = 1e10f; }
    FOR_SLOTS(INIT_S)
#undef INIT_S

    float lx, ly, lz;
    {
        float4 q0 = P[0];                       // seed = index 0
        lx = q0.x; ly = q0.y; lz = q0.z;
        if (blk == 0 && tid == 0) s_out[(size_t)b * NPOINT + 0] = q0;
    }
    __syncthreads();                            // staging visible

    for (int it = 1; it < NPOINT; ++it){
        float    bv = -1.0f;                    // all min_d >= 0
        uint32_t bi = 0;                        // GLOBAL point index
        // slots ascend in global index -> strict > keeps first occurrence
#define DO_S(s) { \
        float2 c = xy[(s) * FPS_T + tid]; \
        float dx = fsubrn(c.x, lx); \
        float dy = fsubrn(c.y, ly); \
        float dz = fsubrn(z##s, lz); \
        float d  = faddrn(faddrn(fmulrn(dx,dx), fmulrn(dy,dy)), fmulrn(dz,dz)); \
        md##s = fminf(md##s, d); \
        if (md##s > bv){ bv = md##s; bi = (uint32_t)(base + (s) * FPS_T + tid); } }
        FOR_SLOTS(DO_S)
#undef DO_S

        // ---- per-wave reduce (DPP, uniform) ----
        uint32_t vb    = __float_as_uint(bv);
        uint32_t gmaxw = wave_max_uniform(vb);
        uint32_t gidxw = wave_max_uniform((vb == gmaxw) ? ~bi : 0u);
        const int par = it & 1;
        if (lane == 0)
            red[par][wv] = ((unsigned long long)gmaxw << 32) | gidxw;
        __syncthreads();                        // 4-wave barrier (cheap)
        // ---- block combine: 4 entries, quad DPP ----
        unsigned long long kblk = quad_max_u64(red[par][lane & 3]); // never 0

        // ---- publish + poll 4-entry mailbox (agent scope) ----
        unsigned long long* slot = mbox + (size_t)it * FPS_NB;
        if (tid == 0)
            __hip_atomic_store(&slot[blk], kblk, __ATOMIC_RELAXED,
                               __HIP_MEMORY_SCOPE_AGENT);
        unsigned long long v = 0;
        int guard = 0;
        for (;;){
            if (v == 0)
                v = __hip_atomic_load(&slot[lane & 3], __ATOMIC_RELAXED,
                                      __HIP_MEMORY_SCOPE_AGENT);
            if (__all(v != 0ULL)) break;
            if (++guard > (1 << 20)) return;    // bail: fail fast, never hang
        }
        unsigned long long kmax = quad_max_u64(v);   // global winner, all lanes
        uint32_t gi  = ~((uint32_t)kmax);
        uint32_t giu = (uint32_t)__builtin_amdgcn_readfirstlane((int)gi);
        float4 q = P[giu];                      // uniform -> scalar load path
        lx = q.x; ly = q.y; lz = q.z;
        if (blk == 0 && tid == 0) s_out[(size_t)b * NPOINT + it] = q;
    }
}

// ---------------------------------------------------------------------------
// Kernel 3: exact 16-NN, LDS-TILED. R14 analysis: knn was L2-restream-bound
// (each of 512 rows/batch streamed the 256KB slice; VALU floor ~20us vs
// ~225us observed). Now 8 waves (8 rows) per block share a 1024-point LDS
// tile (16KB, 16 tiles, 2 barriers each): L2 traffic /8, scans become
// contiguous ds_read_b128 (the measured-fast pattern). Selection math,
// key order, merge, gather unchanged -> bit-exact.
// ---------------------------------------------------------------------------
#define KT       1024                 // tile points
#define KNN_T    512                  // threads (8 waves = 8 rows)

__global__ void __launch_bounds__(KNN_T)
__attribute__((amdgpu_waves_per_eu(4, 4)))
knn_kernel(const float* __restrict__ x,
           const float4* __restrict__ pts,
           const float4* __restrict__ s_arr,
           float* __restrict__ out){
    __shared__ float4 tile[KT];       // 16 KiB

    const int wv   = threadIdx.x >> 6;          // wave 0..7 = row
    const int lane = threadIdx.x & 63;
    const int blk  = blockIdx.x;                // 0 .. B_*NPOINT/8 - 1
    const int b    = blk >> 6;                  // 64 blocks per batch
    const int p    = ((blk & 63) << 3) | wv;

    const float4 s = s_arr[(size_t)b * NPOINT + p];
    const float sx = s.x, sy = s.y, sz = s.z, s2 = s.w;
    const float4* P = pts + (size_t)b * N_;

#define FOR_V(F) F(0) F(1) F(2) F(3) F(4) F(5) F(6) F(7) \
                 F(8) F(9) F(10) F(11) F(12) F(13) F(14) F(15)
#define DECLV(t) unsigned long long v##t = ~0ULL;
    FOR_V(DECLV)
#undef DECLV

#define PROC(q, n) { \
        float dot = faddrn(faddrn(fmulrn(sz, (q).z), fmulrn(sy, (q).y)), fmulrn(sx, (q).x)); \
        float d = fsubrn(faddrn(s2, (q).w), fmulrn(2.0f, dot)); \
        uint32_t bits = __float_as_uint(d); \
        uint32_t key  = bits ^ (((uint32_t)((int32_t)bits >> 31)) | 0x80000000u); \
        unsigned long long c = ((unsigned long long)key << 32) | (uint32_t)(n); \
        if (c < v15){ \
            bool lt0=c<v0,  lt1=c<v1,  lt2=c<v2,  lt3=c<v3; \
            bool lt4=c<v4,  lt5=c<v5,  lt6=c<v6,  lt7=c<v7; \
            bool lt8=c<v8,  lt9=c<v9,  lt10=c<v10, lt11=c<v11; \
            bool lt12=c<v12, lt13=c<v13, lt14=c<v14; \
            v15 = lt14 ? v14 : c; \
            v14 = lt14 ? (lt13 ? v13 : c) : v14; \
            v13 = lt13 ? (lt12 ? v12 : c) : v13; \
            v12 = lt12 ? (lt11 ? v11 : c) : v12; \
            v11 = lt11 ? (lt10 ? v10 : c) : v11; \
            v10 = lt10 ? (lt9  ? v9  : c) : v10; \
            v9  = lt9  ? (lt8  ? v8  : c) : v9;  \
            v8  = lt8  ? (lt7  ? v7  : c) : v8;  \
            v7  = lt7  ? (lt6  ? v6  : c) : v7;  \
            v6  = lt6  ? (lt5  ? v5  : c) : v6;  \
            v5  = lt5  ? (lt4  ? v4  : c) : v5;  \
            v4  = lt4  ? (lt3  ? v3  : c) : v4;  \
            v3  = lt3  ? (lt2  ? v2  : c) : v3;  \
            v2  = lt2  ? (lt1  ? v1  : c) : v2;  \
            v1  = lt1  ? (lt0  ? v0  : c) : v1;  \
            v0  = lt0  ? c : v0; \
        } }

    for (int t = 0; t < N_/KT; ++t){
        // stage tile: 512 threads x 2 float4 (coalesced, L2-resident source)
        float4 a0 = P[t*KT + threadIdx.x];
        float4 a1 = P[t*KT + threadIdx.x + KNN_T];
        __syncthreads();                        // prev scan done before overwrite
        tile[threadIdx.x]          = a0;
        tile[threadIdx.x + KNN_T]  = a1;
        __syncthreads();                        // tile visible
        // scan tile: 16 groups, contiguous ds_read_b128 per lane
        #pragma unroll 4
        for (int g = 0; g < KT/64; ++g){
            const int n = t*KT + (g << 6) + lane;
            float4 q = tile[(g << 6) + lane];
            PROC(q, n)
        }
    }
#undef PROC

    // merge: 16 rounds of wave-min over per-lane heads; winner lane consumes.
    uint32_t myidx = 0;
    const int myr = lane >> 2;
    #pragma unroll 1
    for (int r = 0; r < KNN_; ++r){
        unsigned long long h = v0;
        unsigned long long g = h;
        #pragma unroll
        for (int off = 1; off < 64; off <<= 1){
            unsigned long long o = __shfl_xor(g, off, 64);
            if (o < g) g = o;
        }
        if (h == g){                          // unique winner (idx is unique)
            v0=v1; v1=v2; v2=v3; v3=v4; v4=v5; v5=v6; v6=v7; v7=v8;
            v8=v9; v9=v10; v10=v11; v11=v12; v12=v13; v13=v14; v14=v15;
            v15=~0ULL;
        }
        if (myr == r) myidx = (uint32_t)g;    // keep idx of my output row
    }

    // gather + write: lane l handles neighbor r=l>>2, channels 4*(l&3)..+3
    const int c4 = lane & 3;
    const float4* X4 = (const float4*)x;
    float4 valq = X4[((size_t)b * N_ + myidx) * 4 + c4];
    float4* O4 = (float4*)out;
    O4[(((size_t)b * NPOINT + p) * KNN_ + myr) * 4 + c4] = valq;
}

// ---------------------------------------------------------------------------
extern "C" void kernel_launch(void* const* d_in, const int* in_sizes, int n_in,
                              void* d_out, int out_size, void* d_ws, size_t ws_size,
                              hipStream_t stream) {
    const float* x = (const float*)d_in[0];
    float* out = (float*)d_out;

    // workspace: [pts: 2MB][s_arr: 64KB][mailbox: 128KB]
    const size_t pts_bytes  = (size_t)B_ * N_ * sizeof(float4);
    const size_t s_bytes    = (size_t)B_ * NPOINT * sizeof(float4);
    const size_t part_bytes = (size_t)MBOX_N * sizeof(unsigned long long);
    if (ws_size < pts_bytes + s_bytes + part_bytes) return;  // visible failure
    float4* pts   = (float4*)d_ws;
    float4* s_arr = (float4*)((char*)d_ws + pts_bytes);
    unsigned long long* part =
        (unsigned long long*)((char*)d_ws + pts_bytes + s_bytes);

    prep_kernel<<<(B_*N_ + 255)/256, 256, 0, stream>>>(x, pts);
    zero_part_kernel<<<(MBOX_N + 255)/256, 256, 0, stream>>>(part);
    fps_kernel_mb<<<B_*FPS_NB, FPS_T, 0, stream>>>(pts, s_arr, part);
    knn_kernel<<<(B_*NPOINT)/8, KNN_T, 0, stream>>>(x, pts, s_arr, out);
}

// Round 18
// 1014.938 us; speedup vs baseline: 2.2473x; 1.1526x over previous
//
#include <hip/hip_runtime.h>
#include <hip/hip_bf16.h>
#include <stdint.h>

// Problem constants (from reference)
#define B_      8
#define N_      16384
#define NPOINT  512
#define KNN_    16
#define C_      16

// Exact IEEE f32 ops — bit-match the numpy (ref=np) lowering:
//   p2/s2 : np.sum(v*v,-1)  -> pairwise small-n ASCENDING:  (x2+y2)+z2, no FMA
//   FPS d : np.sum(dd*dd,-1)-> ASCENDING:  (dx2+dy2)+dz2, no FMA
//   dot   : np.einsum unopt -> sum_of_products_contig_two remainder switch,
//           DESCENDING fallthrough:  ((sz*pz) + sy*py) + sx*px, no FMA
//   dist  : (s2 + p2) - 2*dot   elementwise, no FMA
__device__ __forceinline__ float fmulrn(float a, float b){ return __fmul_rn(a,b); }
__device__ __forceinline__ float faddrn(float a, float b){ return __fadd_rn(a,b); }
__device__ __forceinline__ float fsubrn(float a, float b){ return __fsub_rn(a,b); }

// ---------------------------------------------------------------------------
// DPP reductions (VALU pipe, zero LDS ops).
// ---------------------------------------------------------------------------
__device__ __forceinline__ uint32_t umax_(uint32_t a, uint32_t b){ return a > b ? a : b; }

__device__ __forceinline__ uint32_t row16_max(uint32_t x){
    uint32_t t;
    t = (uint32_t)__builtin_amdgcn_update_dpp((int)x, (int)x, 0x111, 0xf, 0xf, false); x = umax_(x, t);
    t = (uint32_t)__builtin_amdgcn_update_dpp((int)x, (int)x, 0x112, 0xf, 0xf, false); x = umax_(x, t);
    t = (uint32_t)__builtin_amdgcn_update_dpp((int)x, (int)x, 0x114, 0xf, 0xf, false); x = umax_(x, t);
    t = (uint32_t)__builtin_amdgcn_update_dpp((int)x, (int)x, 0x118, 0xf, 0xf, false); x = umax_(x, t);
    return x;
}

__device__ __forceinline__ uint32_t wave_max_uniform(uint32_t x){
    x = row16_max(x);
    uint32_t a = (uint32_t)__builtin_amdgcn_readlane((int)x, 15);
    uint32_t b = (uint32_t)__builtin_amdgcn_readlane((int)x, 31);
    uint32_t c = (uint32_t)__builtin_amdgcn_readlane((int)x, 47);
    uint32_t d = (uint32_t)__builtin_amdgcn_readlane((int)x, 63);
    return umax_(umax_(a, b), umax_(c, d));
}

// u64 max across each quad (lanes 4k..4k+3): 2 quad_perm DPP steps.
__device__ __forceinline__ unsigned long long quad_max_u64(unsigned long long k){
    uint32_t lo = (uint32_t)k, hi = (uint32_t)(k >> 32);
    {   // quad_perm [1,0,3,2] = 0xB1
        uint32_t olo = (uint32_t)__builtin_amdgcn_update_dpp((int)lo, (int)lo, 0xB1, 0xf, 0xf, false);
        uint32_t ohi = (uint32_t)__builtin_amdgcn_update_dpp((int)hi, (int)hi, 0xB1, 0xf, 0xf, false);
        bool take = (ohi > hi) || (ohi == hi && olo > lo);
        hi = take ? ohi : hi; lo = take ? olo : lo;
    }
    {   // quad_perm [2,3,0,1] = 0x4E
        uint32_t olo = (uint32_t)__builtin_amdgcn_update_dpp((int)lo, (int)lo, 0x4E, 0xf, 0xf, false);
        uint32_t ohi = (uint32_t)__builtin_amdgcn_update_dpp((int)hi, (int)hi, 0x4E, 0xf, 0xf, false);
        bool take = (ohi > hi) || (ohi == hi && olo > lo);
        hi = take ? ohi : hi; lo = take ? olo : lo;
    }
    return ((unsigned long long)hi << 32) | lo;
}

// ---------------------------------------------------------------------------
// Kernel 1: pack {x, y, z, p2} per point.  p2 = (x*x + y*y) + z*z  (ascending).
// ---------------------------------------------------------------------------
__global__ void prep_kernel(const float* __restrict__ x, float4* __restrict__ pts){
    int i = blockIdx.x * blockDim.x + threadIdx.x;   // 0 .. B_*N_-1
    if (i >= B_ * N_) return;
    const float4* x4 = (const float4*)x;             // x row = 16 floats = 4 float4
    float4 q = x4[(size_t)i * 4];                    // channels 0..3: x,y,z,c3
    float p2 = faddrn(faddrn(fmulrn(q.x,q.x), fmulrn(q.y,q.y)), fmulrn(q.z,q.z));
    pts[i] = make_float4(q.x, q.y, q.z, p2);
}

// ---------------------------------------------------------------------------
// Kernel 1b: zero the mailbox (every launch — graph replays reuse ws).
// ---------------------------------------------------------------------------
#define FPS_NB   4
#define MBOX_N   (B_ * NPOINT * FPS_NB)    // 16384 u64 = 128 KiB
__global__ void zero_part_kernel(unsigned long long* __restrict__ part){
    int i = blockIdx.x * blockDim.x + threadIdx.x;
    if (i < MBOX_N) part[i] = 0ULL;
}

// ---------------------------------------------------------------------------
// Kernel 2: multi-block FPS — R13 protocol (passed R13: 786us, R15) +
// defensive clamp (no-op for valid winners; converts any protocol bug into
// a diagnosable wrong answer instead of a GPU fault). 4 blocks x 1024 thr x
// 4 slots, 4-entry block mailbox, DPP reduces, u64 keys {val_bits, ~idx},
// nonzero==ready, re-zeroed per launch, bounded spin bails out.
// NOTE (R16/R17 post-mortem): the two-pass threshold knn was retired after
// two failures; fps was never implicated (this code passed twice verbatim).
// ---------------------------------------------------------------------------
#define FPS_T    1024
#define FPS_NW   (FPS_T/64)          // 16 waves
#define SLICE    (N_ / FPS_NB)       // 4096 points per block
#define FOR_S4(F) F(0) F(1) F(2) F(3)

__global__ void __launch_bounds__(FPS_T)
fps_kernel_mb(const float4* __restrict__ pts, float4* __restrict__ s_out,
              unsigned long long* __restrict__ part){
    __shared__ float2   xy[SLICE];              // 32 KiB slice of (x,y)
    __shared__ uint32_t red_v[2][FPS_NW];
    __shared__ uint32_t red_i[2][FPS_NW];

    const int b    = blockIdx.x & 7;            // batch (same XCD per batch)
    const int blk  = blockIdx.x >> 3;           // sub-block 0..FPS_NB-1
    const int tid  = threadIdx.x;
    const int lane = tid & 63;
    const int wv   = tid >> 6;
    const int base = blk * SLICE;               // global offset of this slice
    const float4* P = pts + (size_t)b * N_;
    unsigned long long* mbox = part + ((size_t)b * NPOINT) * FPS_NB;

#define DECL_S(s) float z##s, md##s;
    FOR_S4(DECL_S)
#undef DECL_S

#define INIT_S(s) { float4 q = P[base + (s) * FPS_T + tid]; \
        xy[(s) * FPS_T + tid] = make_float2(q.x, q.y); \
        z##s = q.z; md##s = 1e10f; }
    FOR_S4(INIT_S)
#undef INIT_S

    float lx, ly, lz;
    {
        float4 q0 = P[0];                       // seed = index 0
        lx = q0.x; ly = q0.y; lz = q0.z;
        if (blk == 0 && tid == 0) s_out[(size_t)b * NPOINT + 0] = q0;
    }
    __syncthreads();                            // staging visible

    for (int it = 1; it < NPOINT; ++it){
        float    bv = -1.0f;                    // all min_d >= 0
        uint32_t bi = 0;                        // GLOBAL point index
        // slots ascend in global index -> strict > keeps first occurrence
#define DO_S(s) { \
        float2 c = xy[(s) * FPS_T + tid]; \
        float dx = fsubrn(c.x, lx); \
        float dy = fsubrn(c.y, ly); \
        float dz = fsubrn(z##s, lz); \
        float d  = faddrn(faddrn(fmulrn(dx,dx), fmulrn(dy,dy)), fmulrn(dz,dz)); \
        md##s = fminf(md##s, d); \
        if (md##s > bv){ bv = md##s; bi = (uint32_t)(base + (s) * FPS_T + tid); } }
        FOR_S4(DO_S)
#undef DO_S

        // ---- in-block reduce (DPP, uniform) ----
        uint32_t vb    = __float_as_uint(bv);
        uint32_t gmaxw = wave_max_uniform(vb);
        uint32_t gidxw = wave_max_uniform((vb == gmaxw) ? ~bi : 0u);
        const int par = it & 1;
        if (lane == 0){ red_v[par][wv] = gmaxw; red_i[par][wv] = gidxw; }
        __syncthreads();
        uint32_t rv = red_v[par][lane & 15];
        uint32_t ri = red_i[par][lane & 15];
        uint32_t gv = (uint32_t)__builtin_amdgcn_readlane((int)row16_max(rv), 15);
        uint32_t gn = (uint32_t)__builtin_amdgcn_readlane(
                          (int)row16_max((rv == gv) ? ri : 0u), 15);
        unsigned long long kblk = ((unsigned long long)gv << 32) | gn; // never 0

        // ---- publish + poll mailbox (agent scope, L1-bypassing) ----
        unsigned long long* slotp = mbox + (size_t)it * FPS_NB;
        if (tid == 0)
            __hip_atomic_store(&slotp[blk], kblk, __ATOMIC_RELAXED,
                               __HIP_MEMORY_SCOPE_AGENT);
        unsigned long long v = 0;
        int guard = 0;
        for (;;){
            if (v == 0)
                v = __hip_atomic_load(&slotp[lane & 3], __ATOMIC_RELAXED,
                                      __HIP_MEMORY_SCOPE_AGENT);
            if (__all(v != 0ULL)) break;
            if (++guard > (1 << 20)) return;    // bail: fail fast, never hang
        }
        unsigned long long kmax = quad_max_u64(v);   // global winner, all lanes
        uint32_t gi  = ~((uint32_t)kmax);
        uint32_t giu = (uint32_t)__builtin_amdgcn_readfirstlane((int)gi);
        giu &= (uint32_t)(N_ - 1);              // defensive: in-bounds by design
        float4 q = P[giu];                      // uniform -> scalar load path
        lx = q.x; ly = q.y; lz = q.z;
        if (blk == 0 && tid == 0) s_out[(size_t)b * NPOINT + it] = q;
    }
}

// ---------------------------------------------------------------------------
// Kernel 3: exact 16-NN, LDS-TILED full scan (PASSED R15 verbatim; the
// two-pass threshold variant is retired after R16 crash / R17 absmax 4.84).
// 8 waves (8 rows) per block share a 1024-point LDS tile (16KB, 16 tiles,
// 2 barriers each): L2 traffic /8, contiguous ds_read_b128 scans.
// Dependence-free insertion identity (proven R14/R15):
//   v_t' = lt_t ? (lt_{t-1} ? v_{t-1} : c) : v_t,  lt_t = (c < v_t).
// u64 (dist,idx) keys preserve stable-argsort tie order.
// DEFENSIVE: myidx &= N_-1 (no-op when logic holds).
// ---------------------------------------------------------------------------
#define KT       1024                 // tile points
#define KNN_T    512                  // threads (8 waves = 8 rows)

__global__ void __launch_bounds__(KNN_T)
__attribute__((amdgpu_waves_per_eu(4, 4)))
knn_kernel(const float* __restrict__ x,
           const float4* __restrict__ pts,
           const float4* __restrict__ s_arr,
           float* __restrict__ out){
    __shared__ float4 tile[KT];       // 16 KiB

    const int wv   = threadIdx.x >> 6;          // wave 0..7 = row
    const int lane = threadIdx.x & 63;
    const int blk  = blockIdx.x;                // 0 .. B_*NPOINT/8 - 1
    const int b    = blk >> 6;                  // 64 blocks per batch
    const int p    = ((blk & 63) << 3) | wv;

    const float4 s = s_arr[(size_t)b * NPOINT + p];
    const float sx = s.x, sy = s.y, sz = s.z, s2 = s.w;
    const float4* P = pts + (size_t)b * N_;

#define FOR_V(F) F(0) F(1) F(2) F(3) F(4) F(5) F(6) F(7) \
                 F(8) F(9) F(10) F(11) F(12) F(13) F(14) F(15)
#define DECLV(t) unsigned long long v##t = ~0ULL;
    FOR_V(DECLV)
#undef DECLV

#define PROC(q, n) { \
        float dot = faddrn(faddrn(fmulrn(sz, (q).z), fmulrn(sy, (q).y)), fmulrn(sx, (q).x)); \
        float d = fsubrn(faddrn(s2, (q).w), fmulrn(2.0f, dot)); \
        uint32_t bits = __float_as_uint(d); \
        uint32_t key  = bits ^ (((uint32_t)((int32_t)bits >> 31)) | 0x80000000u); \
        unsigned long long c = ((unsigned long long)key << 32) | (uint32_t)(n); \
        if (c < v15){ \
            bool lt0=c<v0,  lt1=c<v1,  lt2=c<v2,  lt3=c<v3; \
            bool lt4=c<v4,  lt5=c<v5,  lt6=c<v6,  lt7=c<v7; \
            bool lt8=c<v8,  lt9=c<v9,  lt10=c<v10, lt11=c<v11; \
            bool lt12=c<v12, lt13=c<v13, lt14=c<v14; \
            v15 = lt14 ? v14 : c; \
            v14 = lt14 ? (lt13 ? v13 : c) : v14; \
            v13 = lt13 ? (lt12 ? v12 : c) : v13; \
            v12 = lt12 ? (lt11 ? v11 : c) : v12; \
            v11 = lt11 ? (lt10 ? v10 : c) : v11; \
            v10 = lt10 ? (lt9  ? v9  : c) : v10; \
            v9  = lt9  ? (lt8  ? v8  : c) : v9;  \
            v8  = lt8  ? (lt7  ? v7  : c) : v8;  \
            v7  = lt7  ? (lt6  ? v6  : c) : v7;  \
            v6  = lt6  ? (lt5  ? v5  : c) : v6;  \
            v5  = lt5  ? (lt4  ? v4  : c) : v5;  \
            v4  = lt4  ? (lt3  ? v3  : c) : v4;  \
            v3  = lt3  ? (lt2  ? v2  : c) : v3;  \
            v2  = lt2  ? (lt1  ? v1  : c) : v2;  \
            v1  = lt1  ? (lt0  ? v0  : c) : v1;  \
            v0  = lt0  ? c : v0; \
        } }

    for (int t = 0; t < N_/KT; ++t){
        // stage tile: 512 threads x 2 float4 (coalesced, L2-resident source)
        float4 a0 = P[t*KT + threadIdx.x];
        float4 a1 = P[t*KT + threadIdx.x + KNN_T];
        __syncthreads();                        // prev scan done before overwrite
        tile[threadIdx.x]          = a0;
        tile[threadIdx.x + KNN_T]  = a1;
        __syncthreads();                        // tile visible
        // scan tile: 16 groups, contiguous ds_read_b128 per lane
        #pragma unroll 4
        for (int g = 0; g < KT/64; ++g){
            const int n = t*KT + (g << 6) + lane;
            float4 q = tile[(g << 6) + lane];
            PROC(q, n)
        }
    }
#undef PROC

    // merge: 16 rounds of wave-min over per-lane heads; winner lane consumes.
    uint32_t myidx = 0;
    const int myr = lane >> 2;
    #pragma unroll 1
    for (int r = 0; r < KNN_; ++r){
        unsigned long long h = v0;
        unsigned long long g = h;
        #pragma unroll
        for (int off = 1; off < 64; off <<= 1){
            unsigned long long o = __shfl_xor(g, off, 64);
            if (o < g) g = o;
        }
        if (h == g){                          // unique winner (idx is unique)
            v0=v1; v1=v2; v2=v3; v3=v4; v4=v5; v5=v6; v6=v7; v7=v8;
            v8=v9; v9=v10; v10=v11; v11=v12; v12=v13; v13=v14; v14=v15;
            v15=~0ULL;
        }
        if (myr == r) myidx = (uint32_t)g;    // keep idx of my output row
    }
    myidx &= (uint32_t)(N_ - 1);              // defensive: in-bounds by design

    // gather + write: lane l handles neighbor r=l>>2, channels 4*(l&3)..+3
    const int c4 = lane & 3;
    const float4* X4 = (const float4*)x;
    float4 valq = X4[((size_t)b * N_ + myidx) * 4 + c4];
    float4* O4 = (float4*)out;
    O4[(((size_t)b * NPOINT + p) * KNN_ + myr) * 4 + c4] = valq;
}

// ---------------------------------------------------------------------------
extern "C" void kernel_launch(void* const* d_in, const int* in_sizes, int n_in,
                              void* d_out, int out_size, void* d_ws, size_t ws_size,
                              hipStream_t stream) {
    const float* x = (const float*)d_in[0];
    float* out = (float*)d_out;

    // workspace: [pts: 2MB][s_arr: 64KB][mailbox: 128KB]
    const size_t pts_bytes  = (size_t)B_ * N_ * sizeof(float4);
    const size_t s_bytes    = (size_t)B_ * NPOINT * sizeof(float4);
    const size_t part_bytes = (size_t)MBOX_N * sizeof(unsigned long long);
    if (ws_size < pts_bytes + s_bytes + part_bytes) return;  // visible failure
    float4* pts   = (float4*)d_ws;
    float4* s_arr = (float4*)((char*)d_ws + pts_bytes);
    unsigned long long* part =
        (unsigned long long*)((char*)d_ws + pts_bytes + s_bytes);

    prep_kernel<<<(B_*N_ + 255)/256, 256, 0, stream>>>(x, pts);
    zero_part_kernel<<<(MBOX_N + 255)/256, 256, 0, stream>>>(part);
    fps_kernel_mb<<<B_*FPS_NB, FPS_T, 0, stream>>>(pts, s_arr, part);
    knn_kernel<<<(B_*NPOINT)/8, KNN_T, 0, stream>>>(x, pts, s_arr, out);
}